// Round 1
// 148.864 us; speedup vs baseline: 1.0429x; 1.0429x over previous
//
#include <hip/hip_runtime.h>

typedef _Float16 half8 __attribute__((ext_vector_type(8)));
typedef float    f32x16 __attribute__((ext_vector_type(16)));

constexpr int kH = 16;    // heads
constexpr int kO = 1024;  // codebook options
constexpr int kA = 128;   // head size
constexpr int kBS = 4096; // B*S positions
constexpr int MTILE = 256; // positions per block (4 msub x 64)
constexpr int NITER = 16;  // option-tiles (32 options) per nhalf
constexpr int NBUF = 4;    // LDS ring depth (3-ahead prefetch)

typedef const __attribute__((address_space(1))) uint32_t* gas_ptr;
typedef __attribute__((address_space(3))) uint32_t* las_ptr;

// ---- Pass 1: split W into fp16 hi/lo planes, packed fragment-major ----
// Packed (halfs): (h*32 + t)*8192 + plane*4096 + ks*512 + lane*8 + j
//   where t = o>>5, lane = half*32 + (o&31), ks = a>>4, half = (a>>3)&1, j = a&7
// Each (tile, plane, ks) chunk is 64 lanes x 16 B contiguous.
__global__ void split_w(const float* __restrict__ w, ushort* __restrict__ wp) {
    const int lane = threadIdx.x & 63;
    const int gw   = blockIdx.x * 4 + (threadIdx.x >> 6);
    const int ks   = lane >> 3;          // (2L)>>4
    const int half = (lane >> 2) & 1;    // ((2L)>>3)&1
    const int j    = (2 * lane) & 7;
#pragma unroll
    for (int q = 0; q < 4; ++q) {
        int r = gw * 4 + q;              // global row: h*1024 + o
        int h = r >> 10, o = r & 1023, t = o >> 5, o31 = o & 31;
        float2 v = *(const float2*)(w + r * kA + lane * 2);
        _Float16 h0 = (_Float16)v.x, h1 = (_Float16)v.y;
        _Float16 l0 = (_Float16)(v.x - (float)h0), l1 = (_Float16)(v.y - (float)h1);
        ushort2 hv = { __builtin_bit_cast(ushort, h0), __builtin_bit_cast(ushort, h1) };
        ushort2 lv = { __builtin_bit_cast(ushort, l0), __builtin_bit_cast(ushort, l1) };
        ushort* d = wp + (h * 32 + t) * 8192 + ks * 512 + (half * 32 + o31) * 8 + j;
        *(ushort2*)d = hv;               // plane 0 (hi)
        *(ushort2*)(d + 4096) = lv;      // plane 1 (lo)
    }
}

// counted-vmcnt phase sync: wait own tile DMA (leave deeper prefetch in
// flight), then block barrier (others' waits done => all chunks visible).
#define PHASE_SYNC(N) do {                                        \
    asm volatile("s_waitcnt vmcnt(" #N ")" ::: "memory");         \
    __builtin_amdgcn_s_barrier();                                 \
    asm volatile("" ::: "memory");                                \
  } while (0)

// ---- Pass 2: 8-wave blocks, ring-4 LDS, 3-ahead DMA prefetch ----
// Wave (nhalf, msub) handles 64 positions (2 row-tiles of 32) x 512 options.
// Per iter: 24 ds_read_b128 feed 48 MFMA (2:1 MFMA:LDS cycle ratio); one
// s_barrier; vmcnt never drained to 0 in steady state (tiles it+1..it+3 fly).
__launch_bounds__(512, 2)
__global__ void vq_argmax_gather(const float* __restrict__ x,
                                 const ushort* __restrict__ wp,
                                 const float* __restrict__ cb,
                                 float* __restrict__ out) {
    __shared__ ushort wtile[NBUF][2][8192];  // 128 KiB ring [buf][nh][plane*4096+ks*512+..]
    __shared__ float red_max[2][MTILE];
    __shared__ int   red_idx[2][MTILE];

    const int tid   = threadIdx.x;
    const int lane  = tid & 63;
    const int wv    = tid >> 6;     // 0..7
    const int nhalf = wv >> 2;      // option half (512 each)
    const int msub  = wv & 3;       // 64-position group
    const int bid   = blockIdx.x;
    // XCD-aware: XCD (bid&7) touches only heads {2x,2x+1} -> W+cb L2-resident
    const int h  = ((bid & 7) << 1) | ((bid >> 3) & 1);
    const int p0 = (bid >> 4) * MTILE;

    const int l31  = lane & 31;
    const int half = lane >> 5;

    const ushort* wh_base = wp + h * 32 * 8192;   // this head's packed W

    // DMA one 32-option tile (both nhalves, hi+lo = 32 KB): 32 chunks of
    // 64 lanes x 16 B, 4 per wave. chunk c = wv*4+q: nh = c>>4, rem = c&15.
    auto stage = [&](int it, int buf) {
#pragma unroll
        for (int q = 0; q < 4; ++q) {
            int c   = wv * 4 + q;
            int nh  = c >> 4, rem = c & 15;
            const ushort* g = wh_base + (nh * 16 + it) * 8192 + rem * 512 + lane * 8;
            ushort* l = &wtile[buf][nh][rem * 512];
            __builtin_amdgcn_global_load_lds((gas_ptr)(const void*)g,
                                             (las_ptr)(void*)l, 16, 0, 0);
        }
    };

    stage(0, 0); stage(1, 1); stage(2, 2);   // 12 chunks in flight under x-prep
    asm volatile("" ::: "memory");

    // stationary x fragments for BOTH row-tiles (fp32 -> fp16 hi/lo in-register)
    const int mrow0 = p0 + msub * 64 + l31;
    const float* xb0 = x + (mrow0 * kH + h) * kA + half * 8;
    const float* xb1 = xb0 + 32 * kH * kA;   // +32 positions
    half8 xh0[8], xl0[8], xh1[8], xl1[8];
    auto cvt8 = [&](const float* p, half8& hi, half8& lo) {
        float4 v0 = *(const float4*)(p);
        float4 v1 = *(const float4*)(p + 4);
        float va[8] = { v0.x, v0.y, v0.z, v0.w, v1.x, v1.y, v1.z, v1.w };
#pragma unroll
        for (int j = 0; j < 8; ++j) {
            _Float16 hj = (_Float16)va[j];
            hi[j] = hj;
            lo[j] = (_Float16)(va[j] - (float)hj);
        }
    };
#pragma unroll
    for (int ks = 0; ks < 8; ++ks) {
        cvt8(xb0 + ks * 16, xh0[ks], xl0[ks]);
        cvt8(xb1 + ks * 16, xh1[ks], xl1[ks]);
    }

    float best0 = -1e30f, best1 = -1e30f;
    int   bidx0 = 0,      bidx1 = 0;
    const int nwb = nhalf * (kO / 2);

    // per-acc MFMA order preserved exactly vs previous kernel:
    // wh x xh (ks0..7), wh x xl (ks0..7), wl x xh (ks0..7)
    auto compute = [&](int it) {
        const int buf = it & 3;
        const ushort* lbase = &wtile[buf][nhalf][lane * 8];
        f32x16 acc0 = {}, acc1 = {};
        __builtin_amdgcn_s_setprio(1);
#pragma unroll
        for (int ks = 0; ks < 8; ++ks) {
            half8 wh = *(const half8*)(lbase + ks * 512);
            acc0 = __builtin_amdgcn_mfma_f32_32x32x16_f16(wh, xh0[ks], acc0, 0, 0, 0);
            acc1 = __builtin_amdgcn_mfma_f32_32x32x16_f16(wh, xh1[ks], acc1, 0, 0, 0);
        }
#pragma unroll
        for (int ks = 0; ks < 8; ++ks) {
            half8 wh = *(const half8*)(lbase + ks * 512);   // re-read: keeps VGPR ~190
            acc0 = __builtin_amdgcn_mfma_f32_32x32x16_f16(wh, xl0[ks], acc0, 0, 0, 0);
            acc1 = __builtin_amdgcn_mfma_f32_32x32x16_f16(wh, xl1[ks], acc1, 0, 0, 0);
        }
#pragma unroll
        for (int ks = 0; ks < 8; ++ks) {
            half8 wl = *(const half8*)(lbase + 4096 + ks * 512);
            acc0 = __builtin_amdgcn_mfma_f32_32x32x16_f16(wl, xh0[ks], acc0, 0, 0, 0);
            acc1 = __builtin_amdgcn_mfma_f32_32x32x16_f16(wl, xh1[ks], acc1, 0, 0, 0);
        }
        __builtin_amdgcn_s_setprio(0);

        // fold 16 option-rows per acc into running scalar argmax
        float lv0 = acc0[0]; int lr0 = 0;
#pragma unroll
        for (int r = 1; r < 16; ++r)
            if (acc0[r] > lv0) { lv0 = acc0[r]; lr0 = r; }   // strict >: earliest row wins
        int li0 = nwb + it * 32 + 4 * half + (lr0 & 3) + 8 * (lr0 >> 2);
        if (lv0 > best0) { best0 = lv0; bidx0 = li0; }

        float lv1 = acc1[0]; int lr1 = 0;
#pragma unroll
        for (int r = 1; r < 16; ++r)
            if (acc1[r] > lv1) { lv1 = acc1[r]; lr1 = r; }
        int li1 = nwb + it * 32 + 4 * half + (lr1 & 3) + 8 * (lr1 >> 2);
        if (lv1 > best1) { best1 = lv1; bidx1 = li1; }
    };

    // steady state: outstanding = tiles {it,it+1,it+2} = 12 chunks; wait to 8
    // => tile it landed, deeper prefetch stays in flight across the barrier.
    for (int it = 0; it < NITER - 3; ++it) {   // it = 0..12
        PHASE_SYNC(8);
        stage(it + 3, (it + 3) & 3);           // after barrier: old readers done
        compute(it);
    }
    PHASE_SYNC(8); compute(NITER - 3);         // it=13: {13,14,15} -> wait 8
    PHASE_SYNC(4); compute(NITER - 2);         // it=14: {14,15}    -> wait 4
    PHASE_SYNC(0); compute(NITER - 1);         // it=15: {15}       -> wait 0

    // merge lane halves (disjoint option rows, same position column)
    {
        float om = __shfl_xor(best0, 32, 64);
        int   oi = __shfl_xor(bidx0, 32, 64);
        if (om > best0 || (om == best0 && oi < bidx0)) { best0 = om; bidx0 = oi; }
        om = __shfl_xor(best1, 32, 64);
        oi = __shfl_xor(bidx1, 32, 64);
        if (om > best1 || (om == best1 && oi < bidx1)) { best1 = om; bidx1 = oi; }
    }
    if (half == 0) {
        red_max[nhalf][msub * 64 + l31]      = best0;
        red_idx[nhalf][msub * 64 + l31]      = bidx0;
        red_max[nhalf][msub * 64 + 32 + l31] = best1;
        red_idx[nhalf][msub * 64 + 32 + l31] = bidx1;
    }
    __syncthreads();

    // gather: out[p0+row, h, :] = cb[h, argmax, :]
    for (int i = tid; i < MTILE * 32; i += 512) {
        int row = i >> 5, ch = i & 31;
        float m0 = red_max[0][row], m1 = red_max[1][row];
        int o = (m1 > m0) ? red_idx[1][row] : red_idx[0][row]; // ties -> smaller o
        float4 v = *(const float4*)(cb + (h * kO + o) * kA + ch * 4);
        *(float4*)(out + ((p0 + row) * kH + h) * kA + ch * 4) = v;
    }
}

extern "C" void kernel_launch(void* const* d_in, const int* in_sizes, int n_in,
                              void* d_out, int out_size, void* d_ws, size_t ws_size,
                              hipStream_t stream) {
    const float* x  = (const float*)d_in[0];   // [4096,16,128] fp32
    const float* w  = (const float*)d_in[1];   // [16,1024,128] fp32
    const float* cb = (const float*)d_in[2];   // [16,1024,128] fp32
    // d_in[3] = temperature: forward value is temperature-independent
    float* out = (float*)d_out;                // [4096,16,128] fp32

    ushort* wpacked = (ushort*)d_ws;           // 8 MiB packed hi+lo planes

    split_w<<<dim3(1024), dim3(256), 0, stream>>>(w, wpacked);
    vq_argmax_gather<<<dim3((kBS / MTILE) * kH), dim3(512), 0, stream>>>(x, wpacked, cb, out);
}